// Round 13
// baseline (90.693 us; speedup 1.0000x reference)
//
#include <hip/hip_runtime.h>
#include <stdint.h>

#define H_ 224
#define W_ 224
#define NPIX (H_ * W_)          // 50176
#define ROWQ 56                 // dwords per row
#define NFRAMES 256
#define NT 1024
#define NWAVE 16
#define STRIP 14                // rows per wave: 16 waves x 14 = 224
#define TRIW 8224               // 32896 triangle bins / 4 per word

__device__ __forceinline__ uint32_t udot4acc(uint32_t a, uint32_t b, uint32_t c) {
#if __has_builtin(__builtin_amdgcn_udot4)
    return __builtin_amdgcn_udot4(a, b, c, false);
#else
    c += (a & 0xffu) * (b & 0xffu);
    c += ((a >> 8) & 0xffu) * ((b >> 8) & 0xffu);
    c += ((a >> 16) & 0xffu) * ((b >> 16) & 0xffu);
    c += (a >> 24) * (b >> 24);
    return c;
#endif
}

__device__ __forceinline__ uint32_t quant1(float s) {
    float gr = s / 3.0f;
    float v = floorf(gr * 255.0f);
    v = fminf(fmaxf(v, 0.0f), 255.0f);
    return (uint32_t)(int)v;
}

// upper-triangle offset: row i starts at off(i) = i*(513-i)/2 (always integer)
__device__ __forceinline__ uint32_t offtri(uint32_t i) { return (i * (513u - i)) >> 1; }

// symmetrized increment: bin (min,max) of u8-packed triangle histogram
__device__ __forceinline__ void hinc(uint32_t* hist, uint32_t a, uint32_t b) {
    uint32_t i = min(a, b), j = max(a, b);
    uint32_t idx = offtri(i) + (j - i);
    atomicAdd(&hist[idx >> 2], 1u << ((idx & 3u) << 3));
}

// ---------------- single fused kernel: one frame per block ----------------
__global__ __launch_bounds__(NT, 4) void k_all(const float* __restrict__ x,
                                               float* __restrict__ out) {
    __shared__ uint32_t hist[4][TRIW];       // 131584 B: 4 symmetrized triangles
    __shared__ uint32_t firstrow[NWAVE][56]; // 3584 B: strip first rows
    __shared__ uint32_t lastrow[NWAVE][56];  // 3584 B: strip last rows
    __shared__ double red[NWAVE * 8];        // 1024 B

    const int f = blockIdx.x;
    const int bq = f >> 3, fq = f & 7;
    const int tid = threadIdx.x, lane = tid & 63, wave = tid >> 6;

    const float* xb = x + ((size_t)bq * 24 + fq) * NPIX;   // channel stride 8*NPIX
    const float4* xc0 = reinterpret_cast<const float4*>(xb);
    const float4* xc1 = reinterpret_cast<const float4*>(xb + 8 * NPIX);
    const float4* xc2 = reinterpret_cast<const float4*>(xb + 16 * NPIX);

    // zero all 4 histograms (32896 words = 8224 uint4)
    uint4* h4 = reinterpret_cast<uint4*>(&hist[0][0]);
    const uint4 z4 = make_uint4(0u, 0u, 0u, 0u);
    #pragma unroll
    for (int i = 0; i < 8; ++i) h4[tid + (i << 10)] = z4;
    if (tid < 32) h4[tid + 8192] = z4;
    __syncthreads();

    // ---- stream: rows in strips, ALL 4 offsets' atomics fused, no barriers ----
    uint32_t s1 = 0, s2 = 0;
    if (lane < 56) {
        uint32_t prev = 0;
        const int rbase = wave * STRIP;
        for (int rr = 0; rr < STRIP; ++rr) {
            int m = (rbase + rr) * ROWQ + lane;
            float4 av = xc0[m], bv = xc1[m], cv = xc2[m];
            uint32_t v0 = quant1(av.x + bv.x + cv.x);
            uint32_t v1 = quant1(av.y + bv.y + cv.y);
            uint32_t v2 = quant1(av.z + bv.z + cv.z);
            uint32_t v3 = quant1(av.w + bv.w + cv.w);
            uint32_t pk = v0 | (v1 << 8) | (v2 << 16) | (v3 << 24);
            if (rr == 0) firstrow[wave][lane] = pk;
            if (rr == STRIP - 1) lastrow[wave][lane] = pk;
            s1 = udot4acc(pk, 0x01010101u, s1);
            s2 = udot4acc(pk, pk, s2);
            uint32_t nx = __shfl_down(pk, 1, 64);
            uint32_t px = __shfl_up(pk, 1, 64);
            uint32_t Bv1 = (pk >> 8) | (nx << 24);   // cols 4l+1 .. 4l+4 (this row)
            uint32_t Bv2 = (pk << 8) | (px >> 24);   // cols 4l-1 .. 4l+2 (this row)
            #pragma unroll
            for (int k = 0; k < 4; ++k) {
                uint32_t ck = (pk >> (8 * k)) & 0xffu;        // (r, c=4l+k)
                uint32_t b1 = (Bv1 >> (8 * k)) & 0xffu;       // (r, c+1)
                bool m1 = !(lane == 55 && k == 3);            // c <= 222
                if (m1) hinc(hist[0], ck, b1);                // (0,1)
                if (rr > 0) {
                    uint32_t pa = (prev >> (8 * k)) & 0xffu;  // (r-1, c)
                    if (m1) hinc(hist[1], pa, b1);            // (1,1)
                    hinc(hist[2], pa, ck);                    // (1,0)
                    if (!(lane == 0 && k == 0))               // c >= 1
                        hinc(hist[3], pa, (Bv2 >> (8 * k)) & 0xffu);  // (1,-1)
                }
            }
            prev = pk;
        }
    }
    __syncthreads();

    // ---- strip-boundary fixups: 15 row-pairs (14b+13, 14b+14) from LDS stash ----
    if (tid < 840) {
        int b = tid / 56, c = tid % 56;
        uint32_t A  = lastrow[b][c];
        uint32_t Bm = firstrow[b + 1][c];
        uint32_t Bn = (c < 55) ? firstrow[b + 1][c + 1] : 0u;
        uint32_t Bp = (c > 0)  ? firstrow[b + 1][c - 1] : 0u;
        #pragma unroll
        for (int k = 0; k < 4; ++k) {
            uint32_t a = (A >> (8 * k)) & 0xffu;
            hinc(hist[2], a, (Bm >> (8 * k)) & 0xffu);                 // (1,0)
            if (k < 3)       hinc(hist[1], a, (Bm >> (8 * (k + 1))) & 0xffu);
            else if (c < 55) hinc(hist[1], a, Bn & 0xffu);             // (1,1)
            if (k > 0)       hinc(hist[3], a, (Bm >> (8 * (k - 1))) & 0xffu);
            else if (c > 0)  hinc(hist[3], a, Bp >> 24);               // (1,-1)
        }
    }
    __syncthreads();

    // ---- scan 4 triangle histograms: con/dis/hom/asm ----
    double conD = 0.0, disD = 0.0, homD = 0.0, asmD = 0.0;
    const double npv[4] = {49952.0, 49729.0, 49952.0, 49729.0};
    #pragma unroll 1
    for (int h = 0; h < 4; ++h) {
        uint32_t conU = 0, disU = 0, slinU = 0, sdgU = 0;
        float homF = 0.0f;
        for (int it = 0; it < 9; ++it) {
            int wi = tid + (it << 10);
            if (wi < TRIW) {
                uint32_t w = hist[h][wi];
                if (w) {
                    int idx0 = wi << 2;
                    float tf = sqrtf(263169.0f - 8.0f * (float)idx0);
                    int i = (int)((513.0f - tf) * 0.5f);
                    if (i > 255) i = 255;
                    if (i < 0) i = 0;
                    while (i < 255 && (int)offtri(i + 1) <= idx0) ++i;
                    while (i > 0 && (int)offtri(i) > idx0) --i;
                    int j = i + (idx0 - (int)offtri(i));
                    #pragma unroll
                    for (int k = 0; k < 4; ++k) {
                        if (j > 255) { ++i; j = i; }
                        uint32_t s = (w >> (k << 3)) & 0xffu;
                        int d = j - i;
                        conU += s * (uint32_t)(d * d);
                        disU += s * (uint32_t)d;
                        homF += (float)s * __builtin_amdgcn_rcpf(1.0f + (float)(d * d));
                        slinU += s * s;
                        if (d == 0) sdgU += s * s;
                        ++j;
                    }
                }
            }
        }
        double np = npv[h];
        conD += (double)conU / np;
        disD += (double)disU / np;
        homD += (double)homF / np;
        asmD += ((double)slinU + (double)sdgU) / (2.0 * np * np);
    }

    // ---- fused reduction of 6 doubles, finalize ----
    double vals[6] = {(double)s1, (double)s2, conD, disD, homD, asmD};
    #pragma unroll
    for (int off = 32; off; off >>= 1) {
        #pragma unroll
        for (int i = 0; i < 6; ++i) vals[i] += __shfl_down(vals[i], off, 64);
    }
    if (lane == 0) {
        #pragma unroll
        for (int i = 0; i < 6; ++i) red[wave * 8 + i] = vals[i];
    }
    __syncthreads();
    if (tid == 0) {
        double acc[6];
        #pragma unroll
        for (int i = 0; i < 6; ++i) {
            double t = red[i];
            for (int w = 1; w < NWAVE; ++w) t += red[w * 8 + i];
            acc[i] = t;
        }
        double N = (double)NPIX;
        double mean = acc[0] / N;
        double var = acc[1] / N - mean * mean;
        if (var < 0.0) var = 0.0;
        float* op = out + f * 6;
        op[0] = (float)sqrt(var);
        op[1] = (float)(acc[2] * 0.25);
        op[2] = (float)(acc[3] * 0.25);
        op[3] = (float)(acc[4] * 0.25);
        op[4] = (float)(acc[5] * 0.25);
        op[5] = (float)sqrt(acc[5] * 0.25);
    }
}

extern "C" void kernel_launch(void* const* d_in, const int* in_sizes, int n_in,
                              void* d_out, int out_size, void* d_ws, size_t ws_size,
                              hipStream_t stream) {
    const float* x = (const float*)d_in[0];
    float* out = (float*)d_out;
    k_all<<<NFRAMES, NT, 0, stream>>>(x, out);
}

// Round 14
// 78.840 us; speedup vs baseline: 1.1503x; 1.1503x over previous
//
#include <hip/hip_runtime.h>
#include <stdint.h>

#define H_ 224
#define W_ 224
#define NPIX (H_ * W_)          // 50176
#define NQ4 (NPIX / 4)          // 12544 dwords per frame
#define NFRAMES 256
#define NT 1024
#define NW 16
#define CROWS 8
#define NCHUNK (H_ / CROWS)     // 28
#define CPX (CROWS * W_)        // 1792 floats per channel per chunk
#define CQ4 (CPX / 4)           // 448 gray dwords per chunk
#define STGF (3 * CPX)          // 5376 floats per staging buffer
#define M10 (223 * 56)          // 12488: dwords with a valid row below
#define TRIW 8224               // 32896 triangle bins / 4 per word

typedef __attribute__((address_space(1))) const uint32_t* gas_t;
typedef __attribute__((address_space(3))) uint32_t* las_t;

__device__ __forceinline__ void gload_lds16(const float* g, float* l) {
    __builtin_amdgcn_global_load_lds((gas_t)g, (las_t)l, 16, 0, 0);
}

__device__ __forceinline__ uint32_t udot4acc(uint32_t a, uint32_t b, uint32_t c) {
#if __has_builtin(__builtin_amdgcn_udot4)
    return __builtin_amdgcn_udot4(a, b, c, false);
#else
    c += (a & 0xffu) * (b & 0xffu);
    c += ((a >> 8) & 0xffu) * ((b >> 8) & 0xffu);
    c += ((a >> 16) & 0xffu) * ((b >> 16) & 0xffu);
    c += (a >> 24) * (b >> 24);
    return c;
#endif
}

// fast quant: 255/3 == 85 exactly; cvt_u32 truncation == floor for s >= 0
__device__ __forceinline__ uint32_t quant1(float s) {
    return min((uint32_t)(s * 85.0f), 255u);
}

// square swizzled u8-packed histogram word index (~3 VALU + atomic)
__device__ __forceinline__ void hist_inc(uint32_t* hist, uint32_t a, uint32_t b) {
    uint32_t w = ((a << 6) | (b >> 2)) ^ (a & 31u);
    atomicAdd(&hist[w], 1u << ((b & 3u) << 3));
}

// upper-triangle offset: row i starts at off(i) = i*(513-i)/2
__device__ __forceinline__ uint32_t offtri(uint32_t i) { return (i * (513u - i)) >> 1; }

// symmetrized triangle increment (tail-only: ~8 VALU + atomic)
__device__ __forceinline__ void hinc_tri(uint32_t* tri, uint32_t a, uint32_t b) {
    uint32_t i = min(a, b), j = max(a, b);
    uint32_t idx = offtri(i) + (j - i);
    atomicAdd(&tri[idx >> 2], 1u << ((idx & 3u) << 3));
}

// ---- square-hist scan: con/dis via udot4 triple, hom, slin + cross term ----
__device__ __forceinline__ void stats_scan(const uint32_t* hist, int tid, int wave, int lane,
                                           double invnp, double inv2np2,
                                           double& conD, double& disD,
                                           double& homD, double& asmD) {
    int conI = 0, disI = 0;
    uint32_t slinU = 0;
    float homF = 0.0f;
    #pragma unroll 4
    for (int itr = 0; itr < 16; ++itr) {
        int m = tid + (itr << 10);
        uint32_t w = hist[m];
        if (w) {                                   // empty word-groups skip (execz)
            int i = m >> 6;
            int c4 = (m & 63) ^ (i & 31);          // undo swizzle: col group
            int d0 = i - (c4 << 2);                // d for k=0
            slinU = udot4acc(w, w, slinU);
            int sb   = (int)udot4acc(w, 0x01010101u, 0u);
            int skb  = (int)udot4acc(w, 0x03020100u, 0u);
            int sk2b = (int)udot4acc(w, 0x09040100u, 0u);
            conI += d0 * d0 * sb - 2 * d0 * skb + sk2b;
            if (d0 == 1 || d0 == 2) {              // mixed-sign |d|: exact path
                int t = 0;
                #pragma unroll
                for (int k = 0; k < 4; ++k) {
                    int d = d0 - k;
                    t += (int)((w >> (k << 3)) & 0xffu) * (d < 0 ? -d : d);
                }
                disI += t;
            } else {
                int t = d0 * sb - skb;             // uniform sign
                disI += (t < 0) ? -t : t;
            }
            #pragma unroll
            for (int k = 0; k < 4; ++k) {
                uint32_t bv = (w >> (k << 3)) & 0xffu;
                int d = d0 - k;
                homF += (float)bv * __builtin_amdgcn_rcpf(1.0f + (float)(d * d));
            }
        }
    }

    // cross term sum h_ij * h_ji over 4x4 byte tiles
    uint32_t scrU = 0;
    #pragma unroll
    for (int q = 0; q < 4; ++q) {
        int s = wave + (q << 4);
        int jt = (lane + s) & 63;
        uint32_t A[4], Bw[4];
        #pragma unroll
        for (int k = 0; k < 4; ++k) {
            int ia = 4 * lane + k;
            A[k]  = hist[((ia << 6) | jt)   ^ (ia & 31)];
            int ib = 4 * jt + k;
            Bw[k] = hist[((ib << 6) | lane) ^ (ib & 31)];
        }
        if ((A[0] | A[1] | A[2] | A[3]) && (Bw[0] | Bw[1] | Bw[2] | Bw[3])) {
            uint32_t x0 = __builtin_amdgcn_perm(Bw[1], Bw[0], 0x05010400u);
            uint32_t x1 = __builtin_amdgcn_perm(Bw[1], Bw[0], 0x07030602u);
            uint32_t x2 = __builtin_amdgcn_perm(Bw[3], Bw[2], 0x05010400u);
            uint32_t x3 = __builtin_amdgcn_perm(Bw[3], Bw[2], 0x07030602u);
            uint32_t t0 = __builtin_amdgcn_perm(x2, x0, 0x05040100u);
            uint32_t t1 = __builtin_amdgcn_perm(x2, x0, 0x07060302u);
            uint32_t t2 = __builtin_amdgcn_perm(x3, x1, 0x05040100u);
            uint32_t t3 = __builtin_amdgcn_perm(x3, x1, 0x07060302u);
            scrU = udot4acc(A[0], t0, scrU);
            scrU = udot4acc(A[1], t1, scrU);
            scrU = udot4acc(A[2], t2, scrU);
            scrU = udot4acc(A[3], t3, scrU);
        }
    }

    conD += (double)conI * invnp;
    disD += (double)disI * invnp;
    homD += (double)homF * invnp;
    asmD += ((double)slinU + (double)scrU) * inv2np2;
}

// ---- triangle-hist scan (R13-validated decode), for the (1,0) offset ----
__device__ __forceinline__ void stats_tri(const uint32_t* tri, int tid,
                                          double invnp, double inv2np2,
                                          double& conD, double& disD,
                                          double& homD, double& asmD) {
    uint32_t conU = 0, disU = 0, slinU = 0, sdgU = 0;
    float homF = 0.0f;
    for (int it = 0; it < 9; ++it) {
        int wi = tid + (it << 10);
        if (wi < TRIW) {
            uint32_t w = tri[wi];
            if (w) {
                int idx0 = wi << 2;
                float tf = sqrtf(263169.0f - 8.0f * (float)idx0);
                int i = (int)((513.0f - tf) * 0.5f);
                if (i > 255) i = 255;
                if (i < 0) i = 0;
                while (i < 255 && (int)offtri(i + 1) <= idx0) ++i;
                while (i > 0 && (int)offtri(i) > idx0) --i;
                int j = i + (idx0 - (int)offtri(i));
                #pragma unroll
                for (int k = 0; k < 4; ++k) {
                    if (j > 255) { ++i; j = i; }
                    uint32_t s = (w >> (k << 3)) & 0xffu;
                    int d = j - i;
                    conU += s * (uint32_t)(d * d);
                    disU += s * (uint32_t)d;
                    homF += (float)s * __builtin_amdgcn_rcpf(1.0f + (float)(d * d));
                    slinU += s * s;
                    if (d == 0) sdgU += s * s;
                    ++j;
                }
            }
        }
    }
    conD += (double)conU * invnp;
    disD += (double)disU * invnp;
    homD += (double)homF * invnp;
    asmD += ((double)slinU + (double)sdgU) * inv2np2;
}

// ---------------- fused kernel: one frame per block ----------------
__global__ __launch_bounds__(NT, 4) void k_fused(const float* __restrict__ x,
                                                 float* __restrict__ out) {
    __shared__ float stage[2][STGF];    // 43008 B DMA staging; later: triangle hist
    __shared__ uint32_t hist[16384];    // 65536 B u8 H[256][256], swizzled
    __shared__ uint32_t gsh[NQ4];       // 50176 B gray frame
    __shared__ double red[NW * 8];      // 1024 B

    const int f = blockIdx.x;
    const int bq = f >> 3, fq = f & 7;
    const int tid = threadIdx.x, lane = tid & 63, wave = tid >> 6;

    const float* xb = x + ((size_t)bq * 24 + fq) * NPIX;   // channel stride 8*NPIX
    float* stg = &stage[0][0];
    uint32_t* triT = reinterpret_cast<uint32_t*>(&stage[0][0]);   // alias (dead after stream)

    uint4* h4 = reinterpret_cast<uint4*>(hist);
    uint4* t4 = reinterpret_cast<uint4*>(triT);
    const uint4 z4 = make_uint4(0u, 0u, 0u, 0u);
    #pragma unroll
    for (int i = 0; i < 4; ++i) h4[tid + (i << 10)] = z4;

    // prologue: DMA chunk 0 -> stage[0]
    if (wave >= 9) {
        int base = (wave - 9) * 3;
        #pragma unroll
        for (int k = 0; k < 3; ++k) {
            int idx = base + k;
            int ch = idx / 7, blk = idx % 7;
            gload_lds16(xb + (size_t)ch * (8 * NPIX) + blk * 256 + lane * 4,
                        stg + ch * CPX + blk * 256);
        }
    }
    __syncthreads();   // full drain once: chunk 0 staged, hist zeroed

    // ---- stream: counted-vmcnt pipeline; quant + std + (0,1) atomics ----
    uint32_t s1 = 0, s2 = 0;
    for (int c = 0; c < NCHUNK; ++c) {
        const int bs = c & 1;
        if (wave >= 9) {
            if (c + 1 < NCHUNK) {
                int base = (wave - 9) * 3;
                #pragma unroll
                for (int k = 0; k < 3; ++k) {
                    int idx = base + k;
                    int ch = idx / 7, blk = idx % 7;
                    gload_lds16(xb + (size_t)ch * (8 * NPIX) + (size_t)(c + 1) * CPX + blk * 256 + lane * 4,
                                stg + (bs ^ 1) * STGF + ch * CPX + blk * 256);
                }
                asm volatile("s_waitcnt vmcnt(3)" ::: "memory");  // chunk c landed; c+1 in flight
            } else {
                asm volatile("s_waitcnt vmcnt(0)" ::: "memory");  // final chunk landed
            }
            __builtin_amdgcn_sched_barrier(0);
        }
        __builtin_amdgcn_s_barrier();          // stage[bs] valid for all waves
        __builtin_amdgcn_sched_barrier(0);
        if (tid < CQ4) {                       // waves 0..6 process chunk c
            const float* st = stg + bs * STGF;
            float4 av = *reinterpret_cast<const float4*>(st + 0 * CPX + 4 * tid);
            float4 bv = *reinterpret_cast<const float4*>(st + 1 * CPX + 4 * tid);
            float4 cv = *reinterpret_cast<const float4*>(st + 2 * CPX + 4 * tid);
            uint32_t v0 = quant1(av.x + bv.x + cv.x);
            uint32_t v1 = quant1(av.y + bv.y + cv.y);
            uint32_t v2 = quant1(av.z + bv.z + cv.z);
            uint32_t v3 = quant1(av.w + bv.w + cv.w);
            uint32_t pk = v0 | (v1 << 8) | (v2 << 16) | (v3 << 24);
            gsh[c * CQ4 + tid] = pk;
            s1 = udot4acc(pk, 0x01010101u, s1);
            s2 = udot4acc(pk, pk, s2);
            uint32_t nx = __shfl_down(pk, 1, 64);
            hist_inc(hist, pk & 0xffu, (pk >> 8) & 0xffu);
            hist_inc(hist, (pk >> 8) & 0xffu, (pk >> 16) & 0xffu);
            hist_inc(hist, (pk >> 16) & 0xffu, pk >> 24);
            int m56 = tid % 56;                // c*448 == 0 mod 56
            if (lane != 63 && m56 != 55)
                hist_inc(hist, pk >> 24, nx & 0xffu);
        }
        __builtin_amdgcn_s_barrier();          // stage[bs] free before next issue
    }
    __syncthreads();                           // full drain: gsh + atomics visible

    // deferred lane-63 cross-dword (0,1) pairs; zero triangle hist (stage now dead)
    if (tid < 196) {
        int m = tid * 64 + 63;
        if (m % 56 != 55) hist_inc(hist, gsh[m] >> 24, gsh[m + 1] & 0xffu);
    }
    #pragma unroll
    for (int i = 0; i < 2; ++i) t4[tid + (i << 10)] = z4;
    if (tid < 8) t4[tid + 2048] = z4;          // 2056 uint4 total
    __syncthreads();

    double conD = 0.0, disD = 0.0, homD = 0.0, asmD = 0.0;
    const double npA = 49952.0, npB = 49729.0;
    const double invA = 1.0 / npA, invB = 1.0 / npB;
    const double invA2 = 1.0 / (2.0 * npA * npA), invB2 = 1.0 / (2.0 * npB * npB);

    stats_scan(hist, tid, wave, lane, invA, invA2, conD, disD, homD, asmD);   // (0,1)
    __syncthreads();
    #pragma unroll
    for (int i = 0; i < 4; ++i) h4[tid + (i << 10)] = z4;
    __syncthreads();

    // ---- merged sweep: (1,1) -> square hist, (1,0) -> triangle ----
    #pragma unroll 2
    for (int it = 0; it < 13; ++it) {
        int m = tid + (it << 10);
        int mc = (m < M10) ? m : (M10 - 1);    // clamp keeps shfl sources exact
        uint32_t A = gsh[mc];
        uint32_t B = gsh[mc + 56];
        uint32_t Bn = __shfl_down(B, 1, 64);
        uint32_t Bv = (B >> 8) | (Bn << 24);
        if (m < M10) {
            // (1,0): all 4 in-dword pairs valid
            hinc_tri(triT, A & 0xffu, B & 0xffu);
            hinc_tri(triT, (A >> 8) & 0xffu, (B >> 8) & 0xffu);
            hinc_tri(triT, (A >> 16) & 0xffu, (B >> 16) & 0xffu);
            hinc_tri(triT, A >> 24, B >> 24);
            // (1,1): shifted
            hist_inc(hist, A & 0xffu, Bv & 0xffu);
            hist_inc(hist, (A >> 8) & 0xffu, (Bv >> 8) & 0xffu);
            hist_inc(hist, (A >> 16) & 0xffu, (Bv >> 16) & 0xffu);
            if (lane != 63 && m % 56 != 55)
                hist_inc(hist, A >> 24, Bv >> 24);
        }
    }
    if (tid < 195) {                           // (1,1) lane-63 boundary fixup
        int m = tid * 64 + 63;
        if (m < M10 && m % 56 != 55)
            hist_inc(hist, gsh[m] >> 24, gsh[m + 57] & 0xffu);
    }
    __syncthreads();
    stats_scan(hist, tid, wave, lane, invB, invB2, conD, disD, homD, asmD);   // (1,1)
    stats_tri(triT, tid, invA, invA2, conD, disD, homD, asmD);                // (1,0)
    __syncthreads();
    #pragma unroll
    for (int i = 0; i < 4; ++i) h4[tid + (i << 10)] = z4;
    __syncthreads();

    // ---- offset (1,-1): flat all-lane sweep ----
    #pragma unroll 2
    for (int it = 0; it < 13; ++it) {
        int m = tid + (it << 10);
        int mc = (m < M10) ? m : (M10 - 1);
        uint32_t A = gsh[mc];
        uint32_t B = gsh[mc + 56];
        uint32_t Bp = __shfl_up(B, 1, 64);
        uint32_t Bv = (B << 8) | (Bp >> 24);
        if (m < M10) {
            if (lane != 0 && m % 56 != 0)
                hist_inc(hist, A & 0xffu, Bv & 0xffu);
            hist_inc(hist, (A >> 8) & 0xffu, (Bv >> 8) & 0xffu);
            hist_inc(hist, (A >> 16) & 0xffu, (Bv >> 16) & 0xffu);
            hist_inc(hist, A >> 24, Bv >> 24);
        }
    }
    if (tid >= 1 && tid < 196) {               // lane-0 boundary fixup
        int m = tid * 64;
        if (m < M10 && m % 56 != 0)
            hist_inc(hist, gsh[m] & 0xffu, gsh[m + 55] >> 24);
    }
    __syncthreads();
    stats_scan(hist, tid, wave, lane, invB, invB2, conD, disD, homD, asmD);   // (1,-1)

    // ---- fused reduction of 6 doubles, finalize ----
    double vals[6] = {(double)s1, (double)s2, conD, disD, homD, asmD};
    #pragma unroll
    for (int off = 32; off; off >>= 1) {
        #pragma unroll
        for (int i = 0; i < 6; ++i) vals[i] += __shfl_down(vals[i], off, 64);
    }
    if (lane == 0) {
        #pragma unroll
        for (int i = 0; i < 6; ++i) red[wave * 8 + i] = vals[i];
    }
    __syncthreads();
    if (tid == 0) {
        double acc[6];
        #pragma unroll
        for (int i = 0; i < 6; ++i) {
            double t = red[i];
            for (int w = 1; w < NW; ++w) t += red[w * 8 + i];
            acc[i] = t;
        }
        double N = (double)NPIX;
        double mean = acc[0] / N;
        double var = acc[1] / N - mean * mean;
        if (var < 0.0) var = 0.0;
        float* op = out + f * 6;
        op[0] = (float)sqrt(var);
        op[1] = (float)(acc[2] * 0.25);
        op[2] = (float)(acc[3] * 0.25);
        op[3] = (float)(acc[4] * 0.25);
        op[4] = (float)(acc[5] * 0.25);
        op[5] = (float)sqrt(acc[5] * 0.25);
    }
}

extern "C" void kernel_launch(void* const* d_in, const int* in_sizes, int n_in,
                              void* d_out, int out_size, void* d_ws, size_t ws_size,
                              hipStream_t stream) {
    const float* x = (const float*)d_in[0];
    float* out = (float*)d_out;
    k_fused<<<NFRAMES, NT, 0, stream>>>(x, out);
}